// Round 1
// 186.236 us; speedup vs baseline: 1.1280x; 1.1280x over previous
//
#include <hip/hip_runtime.h>
#include <stdint.h>

typedef __attribute__((ext_vector_type(4))) float f32x4;
typedef __attribute__((ext_vector_type(8))) short s16x8;

#define BB 4
#define NN 4096
#define FF 32
#define BNF (BB*NN*FF)   // 524288

// ---------- bf16 helpers ----------
static __device__ __forceinline__ float bf2f(uint16_t u) {
    union { uint32_t i; float f; } v; v.i = ((uint32_t)u) << 16; return v.f;
}
static __device__ __forceinline__ uint16_t f2bf(float f) {
    union { float f; uint32_t i; } v; v.f = f;
    uint32_t r = v.i + 0x7FFFu + ((v.i >> 16) & 1u);
    return (uint16_t)(r >> 16);
}
static __device__ __forceinline__ float sig_acc(float x) { return 1.0f / (1.0f + expf(-x)); }

// ---------- adj fp32 -> bf16 (once; both GEMMs then read bf16) ----------
__global__ __launch_bounds__(256) void cvt_adj(const float* __restrict__ a,
                                               uint16_t* __restrict__ ab)
{
    size_t i = ((size_t)blockIdx.x * 256 + threadIdx.x) * 8;   // grid 8192 -> 16.7M elems
    float4 v0 = *(const float4*)(a + i);
    float4 v1 = *(const float4*)(a + i + 4);
    union { uint4 u; uint16_t e[8]; } o;
    o.e[0] = f2bf(v0.x); o.e[1] = f2bf(v0.y); o.e[2] = f2bf(v0.z); o.e[3] = f2bf(v0.w);
    o.e[4] = f2bf(v1.x); o.e[5] = f2bf(v1.y); o.e[6] = f2bf(v1.z); o.e[7] = f2bf(v1.w);
    *(uint4*)(ab + i) = o.u;
}

// ---------- prep W: fp32 [14][32][64] -> bf16 Wp[gp][col][slot^swz][k&7] ----------
// B-fragment layout for mfma_f32_16x16x32_bf16: lane l holds B[k=(l>>4)*8+e][col=l&15]
// -> store W col-major in f.  Row = (gp,col) = 128B = 8 16B slots; slot sl = (g&1)*4+(k>>3),
// phys slot = sl ^ (col&7)  (bank-spread so frag ds_read_b128 is ~2-way).
__global__ __launch_bounds__(256) void prep_w(const float* __restrict__ Wf,
                                              uint16_t* __restrict__ Wp)
{
    int idx = blockIdx.x * 256 + threadIdx.x;   // 14*32*64 = 28672, grid 112
    int g   = idx >> 11;
    int k   = (idx >> 6) & 31;
    int col = idx & 63;
    uint16_t v = f2bf(Wf[idx]);                 // Wf[g][k][col]
    int gp = g >> 1;
    int sl = ((g & 1) << 2) | (k >> 3);
    int ph = sl ^ (col & 7);
    Wp[((gp * 64 + col) * 64) + ph * 8 + (k & 7)] = v;
}

// ---------- pack: state [B][N][F] fp32 -> dst[tensor*128 + b*32 + f][n] bf16 ----------
__global__ __launch_bounds__(256) void pack_kernel(
    const float* __restrict__ s0, const float* __restrict__ s1,
    uint16_t* __restrict__ dst)
{
    int bid = blockIdx.x;
    int tensor = bid >> 8;
    int b = (bid >> 6) & 3;
    int ntile = bid & 63;
    const float* src = tensor ? s1 : s0;
    int n0 = ntile * 64;
    __shared__ uint16_t tl[32][65];
    int t = threadIdx.x;
    {
        int i = t >> 2, ch = t & 3;       // node i (0..63), f-chunk ch (8 floats)
        size_t idx = ((size_t)(b * NN + n0 + i)) * FF + ch * 8;
        float4 v0 = *(const float4*)(src + idx);
        float4 v1 = *(const float4*)(src + idx + 4);
        uint16_t e[8] = { f2bf(v0.x), f2bf(v0.y), f2bf(v0.z), f2bf(v0.w),
                          f2bf(v1.x), f2bf(v1.y), f2bf(v1.z), f2bf(v1.w) };
        #pragma unroll
        for (int k = 0; k < 8; k++) tl[ch * 8 + k][i] = e[k];
    }
    __syncthreads();
    {
        int f = t >> 3, ch = t & 7;
        union { uint4 u; uint16_t e[8]; } v;
        #pragma unroll
        for (int k = 0; k < 8; k++) v.e[k] = tl[f][ch * 8 + k];
        size_t row = (size_t)(tensor * 128 + b * 32 + f);
        *(uint4*)(dst + row * NN + n0 + ch * 8) = v.u;
    }
}

// ---------- GEMM: out[c][m] = sum_k adj[m][k] * Bt[c][k]; C fixed = 256 ----------
// 128x128 tile, BK=32, 4 waves (2x2 of 64x64), 16x16x32 bf16 MFMA  [validated R3<->R4]
__global__ __launch_bounds__(256) void gemm_kernel(
    const void* __restrict__ Av,      // adj: bf16 (isf32A=0) or fp32 (isf32A=1)
    const uint16_t* __restrict__ Bt,  // [256][4096] bf16
    float* __restrict__ part, uint16_t* __restrict__ Cb,
    int kLen, int direct, int isf32A)
{
    int mt = blockIdx.x, nt = blockIdx.y, ks = blockIdx.z;
    int m0 = mt * 128, c0 = nt * 128, k0 = ks * kLen;
    __shared__ __align__(16) uint16_t aL[128 * 32];
    __shared__ __align__(16) uint16_t bL[128 * 32];
    int t = threadIdx.x;
    int lane = t & 63, w = t >> 6;
    int wm = (w & 1) * 64, wn = (w >> 1) * 64;
    int lm = lane & 15, lk = lane >> 4;

    const uint16_t* A16 = (const uint16_t*)Av;
    const float*    Af  = (const float*)Av;

    f32x4 acc[4][4] = {};

    for (int kk = k0; kk < k0 + kLen; kk += 32) {
        union { uint4 u; uint16_t e[8]; } sa[2], sb[2];
        #pragma unroll
        for (int q = 0; q < 2; q++) {
            int pos = q * 4096 + t * 16;             // byte offset into 8KB tile
            int row = pos >> 6;                      // 64 B per tile row
            int col = (pos & 63) >> 1;               // bf16 element within row
            size_t aidx = (size_t)(m0 + row) * 4096 + kk + col;
            size_t bidx = (size_t)(c0 + row) * 4096 + kk + col;
            if (!isf32A) {
                sa[q].u = *(const uint4*)(A16 + aidx);
            } else {
                union { uint4 u[2]; float f[8]; } va;
                va.u[0] = *(const uint4*)(Af + aidx);
                va.u[1] = *(const uint4*)(Af + aidx + 4);
                #pragma unroll
                for (int k = 0; k < 8; k++) sa[q].e[k] = f2bf(va.f[k]);
            }
            sb[q].u = *(const uint4*)(Bt + bidx);
        }
        #pragma unroll
        for (int q = 0; q < 2; q++) {
            int pos = q * 4096 + t * 16;
            *(uint4*)((char*)aL + pos) = sa[q].u;
            *(uint4*)((char*)bL + pos) = sb[q].u;
        }
        __syncthreads();
        s16x8 af[4], bfr[4];
        #pragma unroll
        for (int i = 0; i < 4; i++)
            af[i] = *(const s16x8*)(aL + (wm + i * 16 + lm) * 32 + lk * 8);
        #pragma unroll
        for (int j = 0; j < 4; j++)
            bfr[j] = *(const s16x8*)(bL + (wn + j * 16 + lm) * 32 + lk * 8);
        #pragma unroll
        for (int i = 0; i < 4; i++)
            #pragma unroll
            for (int j = 0; j < 4; j++)
                acc[i][j] = __builtin_amdgcn_mfma_f32_16x16x32_bf16(af[i], bfr[j], acc[i][j], 0, 0, 0);
        __syncthreads();
    }

    // C/D layout: col=lane&15 (c dim), row=(lane>>4)*4+reg (m dim)
    int r4 = (lane >> 4) * 4;
    if (direct) {
        #pragma unroll
        for (int i = 0; i < 4; i++)
            #pragma unroll
            for (int j = 0; j < 4; j++) {
                int c = c0 + wn + j * 16 + lm;
                int mr = m0 + wm + i * 16 + r4;
                union { uint2 u; uint16_t e[4]; } v;
                #pragma unroll
                for (int r = 0; r < 4; r++) v.e[r] = f2bf(acc[i][j][r]);
                *(uint2*)(Cb + (size_t)c * 4096 + mr) = v.u;
            }
    } else {
        #pragma unroll
        for (int i = 0; i < 4; i++)
            #pragma unroll
            for (int j = 0; j < 4; j++) {
                int c = c0 + wn + j * 16 + lm;
                int mr = m0 + wm + i * 16 + r4;
                *(f32x4*)(part + ((size_t)ks * 256 + c) * 4096 + mr) = acc[i][j];
            }
    }
}

// ======================================================================
// fuse1: split-K reduce + MFMA dense (8 gates) + GLU + LSTM update.
// Block = (batch b, 64 nodes); 4 waves, wave w owns nodes n0+w*16..+15.
// Per wave: D[node][outcol] = A(state)[node][f] x B(W)[f][outcol] via
// one 16x16x32 MFMA per (gate, 16-col tile): 8*4 = 32 MFMA.
// ======================================================================
__global__ __launch_bounds__(256) void fuse1_kernel(
    const float* __restrict__ part,   // [ns][256][4096] fp32 (ns>0)
    const uint16_t* __restrict__ Cbi, // [256][4096] bf16 (ns==0)
    const uint16_t* __restrict__ Wp,  // packed W (prep_w)
    const float* __restrict__ bf_,
    const float* __restrict__ cf,
    float* __restrict__ cnew, uint16_t* __restrict__ S2t, int ns)
{
    __shared__ __align__(16) uint16_t WL[4 * 64 * 64];  // 32 KB (gates 0..7)
    __shared__ __align__(16) float    AL[64 * 68];      // 17.4 KB (pitch 68)
    __shared__ __align__(16) float    BL[512];
    __shared__ __align__(16) uint16_t H1[32 * 72];      // 4.6 KB (pitch 72)

    int t = threadIdx.x;
    int b = blockIdx.x >> 6, n0 = (blockIdx.x & 63) * 64;

    // stage packed W (linear 32KB copy) + bias
    {
        const uint4* src = (const uint4*)Wp;
        uint4* dst = (uint4*)WL;
        #pragma unroll
        for (int i = 0; i < 8; i++) dst[t + i * 256] = src[t + i * 256];
    }
    if (t < 128) *(float4*)(BL + t * 4) = *(const float4*)(bf_ + t * 4);

    // split-K partial sum -> AL[c'][node], c' 0..31 = ax(f), 32..63 = ah(f)
    {
        int r = t >> 2, ch = t & 3;
        size_t crow = (r < 32) ? (size_t)(b * 32 + r) : (size_t)(128 + b * 32 + (r - 32));
        f32x4 a0, a1, a2, a3;
        if (ns) {
            const float* s0p = part + crow * 4096 + n0 + ch * 16;
            a0 = *(const f32x4*)(s0p);
            a1 = *(const f32x4*)(s0p + 4);
            a2 = *(const f32x4*)(s0p + 8);
            a3 = *(const f32x4*)(s0p + 12);
            for (int ks = 1; ks < ns; ks++) {
                const float* sp = s0p + (size_t)ks * (256 * 4096);
                a0 += *(const f32x4*)(sp);
                a1 += *(const f32x4*)(sp + 4);
                a2 += *(const f32x4*)(sp + 8);
                a3 += *(const f32x4*)(sp + 12);
            }
        } else {
            const uint16_t* cp = Cbi + crow * 4096 + n0 + ch * 16;
            union { uint4 u; uint16_t e[8]; } v0, v1;
            v0.u = *(const uint4*)(cp);
            v1.u = *(const uint4*)(cp + 8);
            #pragma unroll
            for (int k = 0; k < 4; k++) {
                a0[k] = bf2f(v0.e[k]);     a1[k] = bf2f(v0.e[4 + k]);
                a2[k] = bf2f(v1.e[k]);     a3[k] = bf2f(v1.e[4 + k]);
            }
        }
        float* al = AL + r * 68 + ch * 16;
        *(f32x4*)(al) = a0; *(f32x4*)(al + 4) = a1;
        *(f32x4*)(al + 8) = a2; *(f32x4*)(al + 12) = a3;
    }
    __syncthreads();

    int lane = t & 63, w = t >> 6;
    int j = lane & 15, kg = lane >> 4;
    int r4 = kg * 4;

    // prefetch c (hides HBM latency under the MFMA loop)
    float cv[2][4];
    #pragma unroll
    for (int h = 0; h < 2; h++)
        #pragma unroll
        for (int r = 0; r < 4; r++)
            cv[h][r] = cf[((size_t)(b * NN + n0 + w * 16 + r4 + r)) * FF + j + h * 16];

    // A fragments: lane holds A[node = l&15][k = (l>>4)*8 + e]
    s16x8 a_ax, a_ah;
    {
        int col = w * 16 + j;
        #pragma unroll
        for (int e = 0; e < 8; e++) {
            int k = kg * 8 + e;
            a_ax[e] = (short)f2bf(AL[k * 68 + col]);
            a_ah[e] = (short)f2bf(AL[(32 + k) * 68 + col]);
        }
    }

    float s[4][2][4];
    #pragma unroll
    for (int p = 0; p < 4; p++) {
        int g0 = p * 2, g1 = p * 2 + 1;          // even: ax, odd: ah
        f32x4 ac0[4] = {}, ac1[4] = {};
        #pragma unroll
        for (int ct = 0; ct < 4; ct++) {
            int col = ct * 16 + j;
            int ph0 = (kg)     ^ (col & 7);
            int ph1 = (4 + kg) ^ (col & 7);
            s16x8 b0 = *(const s16x8*)(WL + (p * 64 + col) * 64 + ph0 * 8);
            s16x8 b1 = *(const s16x8*)(WL + (p * 64 + col) * 64 + ph1 * 8);
            ac0[ct] = __builtin_amdgcn_mfma_f32_16x16x32_bf16(a_ax, b0, ac0[ct], 0, 0, 0);
            ac1[ct] = __builtin_amdgcn_mfma_f32_16x16x32_bf16(a_ah, b1, ac1[ct], 0, 0, 0);
        }
        // GLU: cols (h*16+j) pair with (32+h*16+j) -> both live in this lane
        #pragma unroll
        for (int h = 0; h < 2; h++)
            #pragma unroll
            for (int r = 0; r < 4; r++) {
                float z0l = ac0[h][r]     + BL[g0 * 64 + h * 16 + j];
                float z0r = ac0[2 + h][r] + BL[g0 * 64 + 32 + h * 16 + j];
                float z1l = ac1[h][r]     + BL[g1 * 64 + h * 16 + j];
                float z1r = ac1[2 + h][r] + BL[g1 * 64 + 32 + h * 16 + j];
                s[p][h][r] = z0l * sig_acc(z0r) + z1l * sig_acc(z1r);
            }
    }

    // LSTM update (pure elementwise in registers)
    #pragma unroll
    for (int h = 0; h < 2; h++) {
        union { uint2 u; uint16_t e[4]; } pk;
        #pragma unroll
        for (int r = 0; r < 4; r++) {
            size_t gidx = ((size_t)(b * NN + n0 + w * 16 + r4 + r)) * FF + j + h * 16;
            float fg = sig_acc(s[0][h][r]);
            float ig = sig_acc(s[1][h][r]);
            float cc = tanhf(s[2][h][r]);
            float og = sig_acc(s[3][h][r]);
            float cn = fg * cv[h][r] + ig * cc;
            cnew[gidx] = cn;
            pk.e[r] = f2bf(og * tanhf(cn));
        }
        *(uint2*)(H1 + (j + h * 16) * 72 + w * 16 + r4) = pk.u;
    }
    __syncthreads();
    {   // pack h1 -> P rows b*32+f (GEMM2 B operand)
        int fr = t >> 3, ch = t & 7;
        uint4 v = *(const uint4*)(H1 + fr * 72 + ch * 8);
        *(uint4*)(S2t + ((size_t)(b * 32 + fr)) * NN + n0 + ch * 8) = v;
    }
}

// ======================================================================
// fuse2: split-K reduce + MFMA dense (6 gates) + memory-state update.
// ======================================================================
__global__ __launch_bounds__(256) void fuse2_kernel(
    const float* __restrict__ part,
    const uint16_t* __restrict__ Cbi,
    const uint16_t* __restrict__ Wp,
    const float* __restrict__ bf_,
    const float* __restrict__ mf,
    float* __restrict__ hnew, float* __restrict__ mnew, int ns)
{
    __shared__ __align__(16) uint16_t WL[3 * 64 * 64];  // 24 KB (gates 8..13)
    __shared__ __align__(16) float    AL[64 * 68];
    __shared__ __align__(16) float    BL[384];

    int t = threadIdx.x;
    int b = blockIdx.x >> 6, n0 = (blockIdx.x & 63) * 64;

    {
        const uint4* src = (const uint4*)(Wp + 4 * 64 * 64);
        uint4* dst = (uint4*)WL;
        #pragma unroll
        for (int i = 0; i < 6; i++) dst[t + i * 256] = src[t + i * 256];
    }
    if (t < 96) *(float4*)(BL + t * 4) = *(const float4*)(bf_ + 512 + t * 4);

    {
        int r = t >> 2, ch = t & 3;
        size_t crow = (r < 32) ? (size_t)(b * 32 + r) : (size_t)(128 + b * 32 + (r - 32));
        f32x4 a0, a1, a2, a3;
        if (ns) {
            const float* s0p = part + crow * 4096 + n0 + ch * 16;
            a0 = *(const f32x4*)(s0p);
            a1 = *(const f32x4*)(s0p + 4);
            a2 = *(const f32x4*)(s0p + 8);
            a3 = *(const f32x4*)(s0p + 12);
            for (int ks = 1; ks < ns; ks++) {
                const float* sp = s0p + (size_t)ks * (256 * 4096);
                a0 += *(const f32x4*)(sp);
                a1 += *(const f32x4*)(sp + 4);
                a2 += *(const f32x4*)(sp + 8);
                a3 += *(const f32x4*)(sp + 12);
            }
        } else {
            const uint16_t* cp = Cbi + crow * 4096 + n0 + ch * 16;
            union { uint4 u; uint16_t e[8]; } v0, v1;
            v0.u = *(const uint4*)(cp);
            v1.u = *(const uint4*)(cp + 8);
            #pragma unroll
            for (int k = 0; k < 4; k++) {
                a0[k] = bf2f(v0.e[k]);     a1[k] = bf2f(v0.e[4 + k]);
                a2[k] = bf2f(v1.e[k]);     a3[k] = bf2f(v1.e[4 + k]);
            }
        }
        float* al = AL + r * 68 + ch * 16;
        *(f32x4*)(al) = a0; *(f32x4*)(al + 4) = a1;
        *(f32x4*)(al + 8) = a2; *(f32x4*)(al + 12) = a3;
    }
    __syncthreads();

    int lane = t & 63, w = t >> 6;
    int j = lane & 15, kg = lane >> 4;
    int r4 = kg * 4;

    float mv[2][4];
    #pragma unroll
    for (int h = 0; h < 2; h++)
        #pragma unroll
        for (int r = 0; r < 4; r++)
            mv[h][r] = mf[((size_t)(b * NN + n0 + w * 16 + r4 + r)) * FF + j + h * 16];

    s16x8 a_h1, a_m;
    {
        int col = w * 16 + j;
        #pragma unroll
        for (int e = 0; e < 8; e++) {
            int k = kg * 8 + e;
            a_h1[e] = (short)f2bf(AL[k * 68 + col]);
            a_m[e]  = (short)f2bf(AL[(32 + k) * 68 + col]);
        }
    }

    float s[3][2][4];
    #pragma unroll
    for (int p = 0; p < 3; p++) {
        int g0 = p * 2, g1 = p * 2 + 1;          // local gates; even: ah1, odd: am
        f32x4 ac0[4] = {}, ac1[4] = {};
        #pragma unroll
        for (int ct = 0; ct < 4; ct++) {
            int col = ct * 16 + j;
            int ph0 = (kg)     ^ (col & 7);
            int ph1 = (4 + kg) ^ (col & 7);
            s16x8 b0 = *(const s16x8*)(WL + (p * 64 + col) * 64 + ph0 * 8);
            s16x8 b1 = *(const s16x8*)(WL + (p * 64 + col) * 64 + ph1 * 8);
            ac0[ct] = __builtin_amdgcn_mfma_f32_16x16x32_bf16(a_h1, b0, ac0[ct], 0, 0, 0);
            ac1[ct] = __builtin_amdgcn_mfma_f32_16x16x32_bf16(a_m, b1, ac1[ct], 0, 0, 0);
        }
        #pragma unroll
        for (int h = 0; h < 2; h++)
            #pragma unroll
            for (int r = 0; r < 4; r++) {
                float z0l = ac0[h][r]     + BL[g0 * 64 + h * 16 + j];
                float z0r = ac0[2 + h][r] + BL[g0 * 64 + 32 + h * 16 + j];
                float z1l = ac1[h][r]     + BL[g1 * 64 + h * 16 + j];
                float z1r = ac1[2 + h][r] + BL[g1 * 64 + 32 + h * 16 + j];
                s[p][h][r] = z0l * sig_acc(z0r) + z1l * sig_acc(z1r);
            }
    }

    #pragma unroll
    for (int h = 0; h < 2; h++)
        #pragma unroll
        for (int r = 0; r < 4; r++) {
            size_t gidx = ((size_t)(b * NN + n0 + w * 16 + r4 + r)) * FF + j + h * 16;
            float i2 = sig_acc(s[0][h][r]);
            float gg = sig_acc(s[1][h][r]);
            float o2 = sig_acc(s[2][h][r]);
            float mn = i2 * mv[h][r] + (1.0f - i2) * gg;
            mnew[gidx] = mn;
            hnew[gidx] = mn * o2;
        }
}

extern "C" void kernel_launch(void* const* d_in, const int* in_sizes, int n_in,
                              void* d_out, int out_size, void* d_ws, size_t ws_size,
                              hipStream_t stream) {
    (void)in_sizes; (void)n_in; (void)out_size;
    const float* x   = (const float*)d_in[0];
    const float* h   = (const float*)d_in[1];
    const float* c   = (const float*)d_in[2];
    const float* m   = (const float*)d_in[3];
    const float* adj = (const float*)d_in[4];
    const float* W   = (const float*)d_in[5];
    const float* bb  = (const float*)d_in[6];
    float* out = (float*)d_out;

    char* ws = (char*)d_ws;
    // tier A (big ws): bf16 adj copy; tier B: fp32-staging GEMM
    int haveAdjb = ws_size >= (size_t)(40u << 20);
    uint16_t* adjb = (uint16_t*)ws;                              // 32 MB (tier A)
    size_t pOff = haveAdjb ? (size_t)(32u << 20) : 0;
    uint16_t* P    = (uint16_t*)(ws + pOff);                     // 2 MB packed B
    uint16_t* Cbuf = (uint16_t*)(ws + pOff + (2u << 20));        // 2 MB GEMM out (ns==0 only)
    uint16_t* Wp   = (uint16_t*)(ws + pOff + (4u << 20));        // 112 KB packed W (1MB slot)
    size_t partOff = pOff + (5u << 20);
    float* part = (float*)(ws + partOff);

    if (ws_size < (6u << 20)) return;   // harness provides >>6MB; safety only
    size_t avail = ws_size - partOff;
    int ns = 0;
    if      (avail >= (size_t)(32u << 20)) ns = 8;
    else if (avail >= (size_t)(16u << 20)) ns = 4;
    else if (avail >= (size_t)( 8u << 20)) ns = 2;
    else if (avail >= (size_t)( 4u << 20)) ns = 1;

    const void* Agemm = haveAdjb ? (const void*)adjb : (const void*)adj;
    int isf32A = haveAdjb ? 0 : 1;

    if (haveAdjb) cvt_adj<<<8192, 256, 0, stream>>>(adj, adjb);
    prep_w<<<112, 256, 0, stream>>>(W, Wp);

    // phase 1: pack x,h -> P rows 0..255; GEMM1 -> part (ax rows 0..127, ah 128..255)
    pack_kernel<<<512, 256, 0, stream>>>(x, h, P);
    if (ns) {
        gemm_kernel<<<dim3(32, 2, ns), 256, 0, stream>>>(Agemm, P, part, nullptr, 4096 / ns, 0, isf32A);
    } else {
        gemm_kernel<<<dim3(32, 2, 1), 256, 0, stream>>>(Agemm, P, nullptr, Cbuf, 4096, 1, isf32A);
    }
    // fuse1: reduce + dense(MFMA) + GLU + LSTM; c_new (fp32) + h1 packed into P rows 0..127
    fuse1_kernel<<<256, 256, 0, stream>>>(part, Cbuf, Wp, bb, c, out + BNF, P, ns);
    // pack m into P rows 128..255
    pack_kernel<<<256, 256, 0, stream>>>(m, m, P + (size_t)128 * NN);
    // phase 2: GEMM2 -> part (ah1 rows 0..127, am 128..255)
    if (ns) {
        gemm_kernel<<<dim3(32, 2, ns), 256, 0, stream>>>(Agemm, P, part, nullptr, 4096 / ns, 0, isf32A);
    } else {
        gemm_kernel<<<dim3(32, 2, 1), 256, 0, stream>>>(Agemm, P, nullptr, Cbuf, 4096, 1, isf32A);
    }
    fuse2_kernel<<<256, 256, 0, stream>>>(part, Cbuf, Wp, bb, m, out, out + 2 * BNF, ns);
}

// Round 2
// 180.506 us; speedup vs baseline: 1.1638x; 1.0317x over previous
//
#include <hip/hip_runtime.h>
#include <stdint.h>

typedef __attribute__((ext_vector_type(4))) float f32x4;
typedef __attribute__((ext_vector_type(8))) short s16x8;

#define BB 4
#define NN 4096
#define FF 32
#define BNF (BB*NN*FF)   // 524288

typedef __attribute__((address_space(3))) void       as3_void;
typedef const __attribute__((address_space(1))) void as1_cvoid;

// ---------- bf16 helpers ----------
static __device__ __forceinline__ float bf2f(uint16_t u) {
    union { uint32_t i; float f; } v; v.i = ((uint32_t)u) << 16; return v.f;
}
static __device__ __forceinline__ uint16_t f2bf(float f) {
    union { float f; uint32_t i; } v; v.f = f;
    uint32_t r = v.i + 0x7FFFu + ((v.i >> 16) & 1u);
    return (uint16_t)(r >> 16);
}
static __device__ __forceinline__ float sig_acc(float x) { return 1.0f / (1.0f + expf(-x)); }

// ======================================================================
// prep: ONE launch for all input-only work.
//   blocks [0, cvtN):            adj fp32 -> bf16            (cvtN = 8192 or 0)
//   blocks [cvtN, cvtN+112):     pack W  -> Wp (MFMA B-frag layout, swizzled)
//   blocks [cvtN+112, +768):     pack x,h -> P rows 0..255; m -> P2 rows 128..255
// ======================================================================
__global__ __launch_bounds__(256) void prep_kernel(
    const float* __restrict__ adj, uint16_t* __restrict__ adjb, int cvtN,
    const float* __restrict__ Wf, uint16_t* __restrict__ Wp,
    const float* __restrict__ x, const float* __restrict__ h,
    const float* __restrict__ m,
    uint16_t* __restrict__ P, uint16_t* __restrict__ P2)
{
    int bid = blockIdx.x;
    int t = threadIdx.x;

    if (bid < cvtN) {
        size_t i = ((size_t)bid * 256 + t) * 8;
        float4 v0 = *(const float4*)(adj + i);
        float4 v1 = *(const float4*)(adj + i + 4);
        union { uint4 u; uint16_t e[8]; } o;
        o.e[0] = f2bf(v0.x); o.e[1] = f2bf(v0.y); o.e[2] = f2bf(v0.z); o.e[3] = f2bf(v0.w);
        o.e[4] = f2bf(v1.x); o.e[5] = f2bf(v1.y); o.e[6] = f2bf(v1.z); o.e[7] = f2bf(v1.w);
        *(uint4*)(adjb + i) = o.u;
        return;
    }
    bid -= cvtN;

    if (bid < 112) {
        // W: fp32 [14][32][64] -> bf16 Wp[gp][col][slot^swz][k&7]
        // B-frag (16x16x32): lane l holds B[k=(l>>4)*8+e][col=l&15]; swizzle spreads banks.
        int idx = bid * 256 + t;                    // 14*32*64 = 28672
        int g   = idx >> 11;
        int k   = (idx >> 6) & 31;
        int col = idx & 63;
        uint16_t v = f2bf(Wf[idx]);                 // Wf[g][k][col]
        int gp = g >> 1;
        int sl = ((g & 1) << 2) | (k >> 3);
        int ph = sl ^ (col & 7);
        Wp[((gp * 64 + col) * 64) + ph * 8 + (k & 7)] = v;
        return;
    }
    bid -= 112;

    // pack: state [B][N][F] fp32 -> dst[rowbase + b*32 + f][n] bf16
    const float* src; uint16_t* dst; int rowbase, b, n0;
    if (bid < 512) {
        int tensor = bid >> 8;
        src = tensor ? h : x; dst = P; rowbase = tensor * 128;
        b = (bid >> 6) & 3; n0 = (bid & 63) * 64;
    } else {
        int q = bid - 512;
        src = m; dst = P2; rowbase = 128;
        b = q >> 6; n0 = (q & 63) * 64;
    }
    __shared__ uint16_t tl[32][65];
    {
        int i = t >> 2, ch = t & 3;       // node i (0..63), f-chunk ch (8 floats)
        size_t idx = ((size_t)(b * NN + n0 + i)) * FF + ch * 8;
        float4 v0 = *(const float4*)(src + idx);
        float4 v1 = *(const float4*)(src + idx + 4);
        uint16_t e[8] = { f2bf(v0.x), f2bf(v0.y), f2bf(v0.z), f2bf(v0.w),
                          f2bf(v1.x), f2bf(v1.y), f2bf(v1.z), f2bf(v1.w) };
        #pragma unroll
        for (int k = 0; k < 8; k++) tl[ch * 8 + k][i] = e[k];
    }
    __syncthreads();
    {
        int f = t >> 3, ch = t & 7;
        union { uint4 u; uint16_t e[8]; } v;
        #pragma unroll
        for (int k = 0; k < 8; k++) v.e[k] = tl[f][ch * 8 + k];
        size_t row = (size_t)(rowbase + b * 32 + f);
        *(uint4*)(dst + row * NN + n0 + ch * 8) = v.u;
    }
}

// ---------- GEMM: out[c][m] = sum_k adj[m][k] * Bt[c][k]; C fixed = 256 ----------
// 128x128 tile, BK=32, 4 waves (2x2 of 64x64), 16x16x32 bf16 MFMA.
// LDS tile rows are 64B = 4 16B slots; phys_slot = logical_slot ^ ((row>>1)&3)
// (both-sides XOR: swizzled GLOBAL source + linear LDS dest + swizzled ds_read).
// bf16 path stages via global_load_lds width=16 (no VGPR round-trip).
__global__ __launch_bounds__(256) void gemm_kernel(
    const void* __restrict__ Av,      // adj: bf16 (isf32A=0) or fp32 (isf32A=1)
    const uint16_t* __restrict__ Bt,  // [256][4096] bf16
    float* __restrict__ part, uint16_t* __restrict__ Cb,
    int kLen, int direct, int isf32A)
{
    int mt = blockIdx.x, nt = blockIdx.y, ks = blockIdx.z;
    int m0 = mt * 128, c0 = nt * 128, k0 = ks * kLen;
    __shared__ __align__(16) uint16_t aL[128 * 32];
    __shared__ __align__(16) uint16_t bL[128 * 32];
    int t = threadIdx.x;
    int lane = t & 63, w = t >> 6;
    int wm = (w & 1) * 64, wn = (w >> 1) * 64;
    int lm = lane & 15, lk = lane >> 4;

    const uint16_t* A16 = (const uint16_t*)Av;
    const float*    Af  = (const float*)Av;

    f32x4 acc[4][4] = {};

    for (int kk = k0; kk < k0 + kLen; kk += 32) {
        if (!isf32A) {
            #pragma unroll
            for (int q = 0; q < 2; q++) {
                int pos  = q * 4096 + t * 16;            // byte offset into 8KB tile
                int row  = pos >> 6;                     // 64 B per tile row
                int slot = ((pos >> 4) & 3) ^ ((row >> 1) & 3);
                int col  = slot * 8;                     // bf16 element within row
                size_t aidx = (size_t)(m0 + row) * 4096 + kk + col;
                size_t bidx = (size_t)(c0 + row) * 4096 + kk + col;
                __builtin_amdgcn_global_load_lds((as1_cvoid*)(A16 + aidx),
                                                 (as3_void*)((char*)aL + pos), 16, 0, 0);
                __builtin_amdgcn_global_load_lds((as1_cvoid*)(Bt + bidx),
                                                 (as3_void*)((char*)bL + pos), 16, 0, 0);
            }
        } else {
            union { uint4 u; uint16_t e[8]; } sa[2], sb[2];
            #pragma unroll
            for (int q = 0; q < 2; q++) {
                int pos  = q * 4096 + t * 16;
                int row  = pos >> 6;
                int slot = ((pos >> 4) & 3) ^ ((row >> 1) & 3);
                int col  = slot * 8;
                size_t aidx = (size_t)(m0 + row) * 4096 + kk + col;
                size_t bidx = (size_t)(c0 + row) * 4096 + kk + col;
                union { uint4 u[2]; float f[8]; } va;
                va.u[0] = *(const uint4*)(Af + aidx);
                va.u[1] = *(const uint4*)(Af + aidx + 4);
                #pragma unroll
                for (int k = 0; k < 8; k++) sa[q].e[k] = f2bf(va.f[k]);
                sb[q].u = *(const uint4*)(Bt + bidx);
            }
            #pragma unroll
            for (int q = 0; q < 2; q++) {
                int pos = q * 4096 + t * 16;
                *(uint4*)((char*)aL + pos) = sa[q].u;
                *(uint4*)((char*)bL + pos) = sb[q].u;
            }
        }
        __syncthreads();
        s16x8 af[4], bfr[4];
        #pragma unroll
        for (int i = 0; i < 4; i++) {
            int r = wm + i * 16 + lm;
            af[i] = *(const s16x8*)(aL + r * 32 + ((lk ^ ((r >> 1) & 3)) * 8));
        }
        #pragma unroll
        for (int j = 0; j < 4; j++) {
            int r = wn + j * 16 + lm;
            bfr[j] = *(const s16x8*)(bL + r * 32 + ((lk ^ ((r >> 1) & 3)) * 8));
        }
        #pragma unroll
        for (int i = 0; i < 4; i++)
            #pragma unroll
            for (int j = 0; j < 4; j++)
                acc[i][j] = __builtin_amdgcn_mfma_f32_16x16x32_bf16(af[i], bfr[j], acc[i][j], 0, 0, 0);
        __syncthreads();
    }

    // C/D layout: col=lane&15 (c dim), row=(lane>>4)*4+reg (m dim)
    int r4 = (lane >> 4) * 4;
    if (direct) {
        #pragma unroll
        for (int i = 0; i < 4; i++)
            #pragma unroll
            for (int j = 0; j < 4; j++) {
                int c = c0 + wn + j * 16 + lm;
                int mr = m0 + wm + i * 16 + r4;
                union { uint2 u; uint16_t e[4]; } v;
                #pragma unroll
                for (int r = 0; r < 4; r++) v.e[r] = f2bf(acc[i][j][r]);
                *(uint2*)(Cb + (size_t)c * 4096 + mr) = v.u;
            }
    } else {
        #pragma unroll
        for (int i = 0; i < 4; i++)
            #pragma unroll
            for (int j = 0; j < 4; j++) {
                int c = c0 + wn + j * 16 + lm;
                int mr = m0 + wm + i * 16 + r4;
                *(f32x4*)(part + ((size_t)ks * 256 + c) * 4096 + mr) = acc[i][j];
            }
    }
}

// ======================================================================
// fuse1: split-K reduce + MFMA dense (8 gates) + GLU + LSTM update.
// Block = (batch b, 64 nodes); 4 waves, wave w owns nodes n0+w*16..+15.
// ======================================================================
__global__ __launch_bounds__(256) void fuse1_kernel(
    const float* __restrict__ part,   // [ns][256][4096] fp32 (ns>0)
    const uint16_t* __restrict__ Cbi, // [256][4096] bf16 (ns==0)
    const uint16_t* __restrict__ Wp,  // packed W (prep)
    const float* __restrict__ bf_,
    const float* __restrict__ cf,
    float* __restrict__ cnew, uint16_t* __restrict__ S2t, int ns)
{
    __shared__ __align__(16) uint16_t WL[4 * 64 * 64];  // 32 KB (gates 0..7)
    __shared__ __align__(16) float    AL[64 * 68];      // 17.4 KB (pitch 68)
    __shared__ __align__(16) float    BL[512];
    __shared__ __align__(16) uint16_t H1[32 * 72];      // 4.6 KB (pitch 72)

    int t = threadIdx.x;
    int b = blockIdx.x >> 6, n0 = (blockIdx.x & 63) * 64;

    // stage packed W (linear 32KB copy) + bias
    {
        const uint4* src = (const uint4*)Wp;
        uint4* dst = (uint4*)WL;
        #pragma unroll
        for (int i = 0; i < 8; i++) dst[t + i * 256] = src[t + i * 256];
    }
    if (t < 128) *(float4*)(BL + t * 4) = *(const float4*)(bf_ + t * 4);

    // split-K partial sum -> AL[c'][node], c' 0..31 = ax(f), 32..63 = ah(f)
    {
        int r = t >> 2, ch = t & 3;
        size_t crow = (r < 32) ? (size_t)(b * 32 + r) : (size_t)(128 + b * 32 + (r - 32));
        f32x4 a0, a1, a2, a3;
        if (ns) {
            const float* s0p = part + crow * 4096 + n0 + ch * 16;
            a0 = *(const f32x4*)(s0p);
            a1 = *(const f32x4*)(s0p + 4);
            a2 = *(const f32x4*)(s0p + 8);
            a3 = *(const f32x4*)(s0p + 12);
            for (int ks = 1; ks < ns; ks++) {
                const float* sp = s0p + (size_t)ks * (256 * 4096);
                a0 += *(const f32x4*)(sp);
                a1 += *(const f32x4*)(sp + 4);
                a2 += *(const f32x4*)(sp + 8);
                a3 += *(const f32x4*)(sp + 12);
            }
        } else {
            const uint16_t* cp = Cbi + crow * 4096 + n0 + ch * 16;
            union { uint4 u; uint16_t e[8]; } v0, v1;
            v0.u = *(const uint4*)(cp);
            v1.u = *(const uint4*)(cp + 8);
            #pragma unroll
            for (int k = 0; k < 4; k++) {
                a0[k] = bf2f(v0.e[k]);     a1[k] = bf2f(v0.e[4 + k]);
                a2[k] = bf2f(v1.e[k]);     a3[k] = bf2f(v1.e[4 + k]);
            }
        }
        float* al = AL + r * 68 + ch * 16;
        *(f32x4*)(al) = a0; *(f32x4*)(al + 4) = a1;
        *(f32x4*)(al + 8) = a2; *(f32x4*)(al + 12) = a3;
    }
    __syncthreads();

    int lane = t & 63, w = t >> 6;
    int j = lane & 15, kg = lane >> 4;
    int r4 = kg * 4;

    // prefetch c (hides HBM latency under the MFMA loop)
    float cv[2][4];
    #pragma unroll
    for (int h = 0; h < 2; h++)
        #pragma unroll
        for (int r = 0; r < 4; r++)
            cv[h][r] = cf[((size_t)(b * NN + n0 + w * 16 + r4 + r)) * FF + j + h * 16];

    // A fragments: lane holds A[node = l&15][k = (l>>4)*8 + e]
    s16x8 a_ax, a_ah;
    {
        int col = w * 16 + j;
        #pragma unroll
        for (int e = 0; e < 8; e++) {
            int k = kg * 8 + e;
            a_ax[e] = (short)f2bf(AL[k * 68 + col]);
            a_ah[e] = (short)f2bf(AL[(32 + k) * 68 + col]);
        }
    }

    float s[4][2][4];
    #pragma unroll
    for (int p = 0; p < 4; p++) {
        int g0 = p * 2, g1 = p * 2 + 1;          // even: ax, odd: ah
        f32x4 ac0[4] = {}, ac1[4] = {};
        #pragma unroll
        for (int ct = 0; ct < 4; ct++) {
            int col = ct * 16 + j;
            int ph0 = (kg)     ^ (col & 7);
            int ph1 = (4 + kg) ^ (col & 7);
            s16x8 b0 = *(const s16x8*)(WL + (p * 64 + col) * 64 + ph0 * 8);
            s16x8 b1 = *(const s16x8*)(WL + (p * 64 + col) * 64 + ph1 * 8);
            ac0[ct] = __builtin_amdgcn_mfma_f32_16x16x32_bf16(a_ax, b0, ac0[ct], 0, 0, 0);
            ac1[ct] = __builtin_amdgcn_mfma_f32_16x16x32_bf16(a_ah, b1, ac1[ct], 0, 0, 0);
        }
        // GLU: cols (h*16+j) pair with (32+h*16+j) -> both live in this lane
        #pragma unroll
        for (int h = 0; h < 2; h++)
            #pragma unroll
            for (int r = 0; r < 4; r++) {
                float z0l = ac0[h][r]     + BL[g0 * 64 + h * 16 + j];
                float z0r = ac0[2 + h][r] + BL[g0 * 64 + 32 + h * 16 + j];
                float z1l = ac1[h][r]     + BL[g1 * 64 + h * 16 + j];
                float z1r = ac1[2 + h][r] + BL[g1 * 64 + 32 + h * 16 + j];
                s[p][h][r] = z0l * sig_acc(z0r) + z1l * sig_acc(z1r);
            }
    }

    // LSTM update (pure elementwise in registers)
    #pragma unroll
    for (int h = 0; h < 2; h++) {
        union { uint2 u; uint16_t e[4]; } pk;
        #pragma unroll
        for (int r = 0; r < 4; r++) {
            size_t gidx = ((size_t)(b * NN + n0 + w * 16 + r4 + r)) * FF + j + h * 16;
            float fg = sig_acc(s[0][h][r]);
            float ig = sig_acc(s[1][h][r]);
            float cc = tanhf(s[2][h][r]);
            float og = sig_acc(s[3][h][r]);
            float cn = fg * cv[h][r] + ig * cc;
            cnew[gidx] = cn;
            pk.e[r] = f2bf(og * tanhf(cn));
        }
        *(uint2*)(H1 + (j + h * 16) * 72 + w * 16 + r4) = pk.u;
    }
    __syncthreads();
    {   // pack h1 -> P2 rows b*32+f (GEMM2 B operand, rows 0..127)
        int fr = t >> 3, ch = t & 7;
        uint4 v = *(const uint4*)(H1 + fr * 72 + ch * 8);
        *(uint4*)(S2t + ((size_t)(b * 32 + fr)) * NN + n0 + ch * 8) = v;
    }
}

// ======================================================================
// fuse2: split-K reduce + MFMA dense (6 gates) + memory-state update.
// ======================================================================
__global__ __launch_bounds__(256) void fuse2_kernel(
    const float* __restrict__ part,
    const uint16_t* __restrict__ Cbi,
    const uint16_t* __restrict__ Wp,
    const float* __restrict__ bf_,
    const float* __restrict__ mf,
    float* __restrict__ hnew, float* __restrict__ mnew, int ns)
{
    __shared__ __align__(16) uint16_t WL[3 * 64 * 64];  // 24 KB (gates 8..13)
    __shared__ __align__(16) float    AL[64 * 68];
    __shared__ __align__(16) float    BL[384];

    int t = threadIdx.x;
    int b = blockIdx.x >> 6, n0 = (blockIdx.x & 63) * 64;

    {
        const uint4* src = (const uint4*)(Wp + 4 * 64 * 64);
        uint4* dst = (uint4*)WL;
        #pragma unroll
        for (int i = 0; i < 6; i++) dst[t + i * 256] = src[t + i * 256];
    }
    if (t < 96) *(float4*)(BL + t * 4) = *(const float4*)(bf_ + 512 + t * 4);

    {
        int r = t >> 2, ch = t & 3;
        size_t crow = (r < 32) ? (size_t)(b * 32 + r) : (size_t)(128 + b * 32 + (r - 32));
        f32x4 a0, a1, a2, a3;
        if (ns) {
            const float* s0p = part + crow * 4096 + n0 + ch * 16;
            a0 = *(const f32x4*)(s0p);
            a1 = *(const f32x4*)(s0p + 4);
            a2 = *(const f32x4*)(s0p + 8);
            a3 = *(const f32x4*)(s0p + 12);
            for (int ks = 1; ks < ns; ks++) {
                const float* sp = s0p + (size_t)ks * (256 * 4096);
                a0 += *(const f32x4*)(sp);
                a1 += *(const f32x4*)(sp + 4);
                a2 += *(const f32x4*)(sp + 8);
                a3 += *(const f32x4*)(sp + 12);
            }
        } else {
            const uint16_t* cp = Cbi + crow * 4096 + n0 + ch * 16;
            union { uint4 u; uint16_t e[8]; } v0, v1;
            v0.u = *(const uint4*)(cp);
            v1.u = *(const uint4*)(cp + 8);
            #pragma unroll
            for (int k = 0; k < 4; k++) {
                a0[k] = bf2f(v0.e[k]);     a1[k] = bf2f(v0.e[4 + k]);
                a2[k] = bf2f(v1.e[k]);     a3[k] = bf2f(v1.e[4 + k]);
            }
        }
        float* al = AL + r * 68 + ch * 16;
        *(f32x4*)(al) = a0; *(f32x4*)(al + 4) = a1;
        *(f32x4*)(al + 8) = a2; *(f32x4*)(al + 12) = a3;
    }
    __syncthreads();

    int lane = t & 63, w = t >> 6;
    int j = lane & 15, kg = lane >> 4;
    int r4 = kg * 4;

    float mv[2][4];
    #pragma unroll
    for (int h = 0; h < 2; h++)
        #pragma unroll
        for (int r = 0; r < 4; r++)
            mv[h][r] = mf[((size_t)(b * NN + n0 + w * 16 + r4 + r)) * FF + j + h * 16];

    s16x8 a_h1, a_m;
    {
        int col = w * 16 + j;
        #pragma unroll
        for (int e = 0; e < 8; e++) {
            int k = kg * 8 + e;
            a_h1[e] = (short)f2bf(AL[k * 68 + col]);
            a_m[e]  = (short)f2bf(AL[(32 + k) * 68 + col]);
        }
    }

    float s[3][2][4];
    #pragma unroll
    for (int p = 0; p < 3; p++) {
        int g0 = p * 2, g1 = p * 2 + 1;          // local gates; even: ah1, odd: am
        f32x4 ac0[4] = {}, ac1[4] = {};
        #pragma unroll
        for (int ct = 0; ct < 4; ct++) {
            int col = ct * 16 + j;
            int ph0 = (kg)     ^ (col & 7);
            int ph1 = (4 + kg) ^ (col & 7);
            s16x8 b0 = *(const s16x8*)(WL + (p * 64 + col) * 64 + ph0 * 8);
            s16x8 b1 = *(const s16x8*)(WL + (p * 64 + col) * 64 + ph1 * 8);
            ac0[ct] = __builtin_amdgcn_mfma_f32_16x16x32_bf16(a_h1, b0, ac0[ct], 0, 0, 0);
            ac1[ct] = __builtin_amdgcn_mfma_f32_16x16x32_bf16(a_m, b1, ac1[ct], 0, 0, 0);
        }
        #pragma unroll
        for (int h = 0; h < 2; h++)
            #pragma unroll
            for (int r = 0; r < 4; r++) {
                float z0l = ac0[h][r]     + BL[g0 * 64 + h * 16 + j];
                float z0r = ac0[2 + h][r] + BL[g0 * 64 + 32 + h * 16 + j];
                float z1l = ac1[h][r]     + BL[g1 * 64 + h * 16 + j];
                float z1r = ac1[2 + h][r] + BL[g1 * 64 + 32 + h * 16 + j];
                s[p][h][r] = z0l * sig_acc(z0r) + z1l * sig_acc(z1r);
            }
    }

    #pragma unroll
    for (int h = 0; h < 2; h++)
        #pragma unroll
        for (int r = 0; r < 4; r++) {
            size_t gidx = ((size_t)(b * NN + n0 + w * 16 + r4 + r)) * FF + j + h * 16;
            float i2 = sig_acc(s[0][h][r]);
            float gg = sig_acc(s[1][h][r]);
            float o2 = sig_acc(s[2][h][r]);
            float mn = i2 * mv[h][r] + (1.0f - i2) * gg;
            mnew[gidx] = mn;
            hnew[gidx] = mn * o2;
        }
}

extern "C" void kernel_launch(void* const* d_in, const int* in_sizes, int n_in,
                              void* d_out, int out_size, void* d_ws, size_t ws_size,
                              hipStream_t stream) {
    (void)in_sizes; (void)n_in; (void)out_size;
    const float* x   = (const float*)d_in[0];
    const float* h   = (const float*)d_in[1];
    const float* c   = (const float*)d_in[2];
    const float* m   = (const float*)d_in[3];
    const float* adj = (const float*)d_in[4];
    const float* W   = (const float*)d_in[5];
    const float* bb  = (const float*)d_in[6];
    float* out = (float*)d_out;

    char* ws = (char*)d_ws;
    // tier A (big ws): bf16 adj copy + global_load_lds GEMM; tier B: fp32-staging GEMM
    int haveAdjb = ws_size >= (size_t)(72u << 20);
    uint16_t* adjb = (uint16_t*)ws;                              // 32 MB (tier A)
    size_t pOff = haveAdjb ? (size_t)(32u << 20) : 0;
    uint16_t* P    = (uint16_t*)(ws + pOff);                     // 2 MB phase-1 B (x,h)
    uint16_t* P2   = (uint16_t*)(ws + pOff + (2u << 20));        // 2 MB phase-2 B (h1,m)
    uint16_t* Cbuf = (uint16_t*)(ws + pOff + (4u << 20));        // 2 MB GEMM out (ns==0 only)
    uint16_t* Wp   = (uint16_t*)(ws + pOff + (6u << 20));        // 112 KB packed W (1MB slot)
    size_t partOff = pOff + (7u << 20);
    float* part = (float*)(ws + partOff);

    if (ws_size < (8u << 20)) return;   // harness ws is ~268MB; safety only
    size_t avail = ws_size - partOff;
    int ns = 0;
    if      (avail >= (size_t)(32u << 20)) ns = 8;
    else if (avail >= (size_t)(16u << 20)) ns = 4;
    else if (avail >= (size_t)( 8u << 20)) ns = 2;
    else if (avail >= (size_t)( 4u << 20)) ns = 1;

    const void* Agemm = haveAdjb ? (const void*)adjb : (const void*)adj;
    int isf32A = haveAdjb ? 0 : 1;
    int cvtN = haveAdjb ? 8192 : 0;

    // ONE prep launch: adj->bf16, W pack, x/h -> P, m -> P2 (all input-only)
    prep_kernel<<<cvtN + 112 + 768, 256, 0, stream>>>(adj, adjb, cvtN, W, Wp, x, h, m, P, P2);

    // phase 1: GEMM1 -> part (ax rows 0..127, ah 128..255)
    if (ns) {
        gemm_kernel<<<dim3(32, 2, ns), 256, 0, stream>>>(Agemm, P, part, nullptr, 4096 / ns, 0, isf32A);
    } else {
        gemm_kernel<<<dim3(32, 2, 1), 256, 0, stream>>>(Agemm, P, nullptr, Cbuf, 4096, 1, isf32A);
    }
    // fuse1: reduce + dense(MFMA) + GLU + LSTM; c_new (fp32) + h1 packed into P2 rows 0..127
    fuse1_kernel<<<256, 256, 0, stream>>>(part, Cbuf, Wp, bb, c, out + BNF, P2, ns);
    // phase 2: GEMM2 -> part (ah1 rows 0..127, am 128..255)
    if (ns) {
        gemm_kernel<<<dim3(32, 2, ns), 256, 0, stream>>>(Agemm, P2, part, nullptr, 4096 / ns, 0, isf32A);
    } else {
        gemm_kernel<<<dim3(32, 2, 1), 256, 0, stream>>>(Agemm, P2, nullptr, Cbuf, 4096, 1, isf32A);
    }
    fuse2_kernel<<<256, 256, 0, stream>>>(part, Cbuf, Wp, bb, m, out, out + 2 * BNF, ns);
}

// Round 4
// 179.610 us; speedup vs baseline: 1.1696x; 1.0050x over previous
//
#include <hip/hip_runtime.h>
#include <stdint.h>

typedef __attribute__((ext_vector_type(4))) float f32x4;
typedef __attribute__((ext_vector_type(8))) short s16x8;

#define BB 4
#define NN 4096
#define FF 32
#define BNF (BB*NN*FF)   // 524288

typedef __attribute__((address_space(3))) void       as3_void;
typedef const __attribute__((address_space(1))) void as1_cvoid;

#define WAITV4() asm volatile("s_waitcnt vmcnt(4)" ::: "memory")
#define WAITV0() asm volatile("s_waitcnt vmcnt(0)" ::: "memory")

// ---------- bf16 helpers ----------
static __device__ __forceinline__ float bf2f(uint16_t u) {
    union { uint32_t i; float f; } v; v.i = ((uint32_t)u) << 16; return v.f;
}
static __device__ __forceinline__ uint16_t f2bf(float f) {
    union { float f; uint32_t i; } v; v.f = f;
    uint32_t r = v.i + 0x7FFFu + ((v.i >> 16) & 1u);
    return (uint16_t)(r >> 16);
}
static __device__ __forceinline__ float sig_acc(float x) { return 1.0f / (1.0f + expf(-x)); }

// per-wave async stage of one ks-partial tile: rows w*16..w*16+15, 64 nodes, fp32.
// 4 x global_load_lds (1KB each: 4 rows x 256B). LDS dest linear (lane*16B).
static __device__ __forceinline__ void issue_tile_f(
    const float* __restrict__ base,   // part + ks*(256*4096)
    float* sb, int w, int lane, int b, int n0)
{
    #pragma unroll
    for (int q = 0; q < 4; q++) {
        int r = w * 16 + q * 4 + (lane >> 4);
        int crow = (r < 32) ? (r + b * 32) : (r + 96 + b * 32);  // 128+b*32+(r-32)
        const float* gp = base + (size_t)crow * 4096 + n0 + (lane & 15) * 4;
        __builtin_amdgcn_global_load_lds((as1_cvoid*)gp,
            (as3_void*)(sb + (w * 16 + q * 4) * 64 + lane * 4), 16, 0, 0);
    }
}

// ======================================================================
// prep: ONE launch for all input-only work.
//   blocks [0, cvtN):            adj fp32 -> bf16            (cvtN = 8192 or 0)
//   blocks [cvtN, cvtN+112):     pack W  -> Wp (MFMA B-frag layout, swizzled)
//   blocks [cvtN+112, +768):     pack x,h -> P rows 0..255; m -> P2 rows 128..255
// ======================================================================
__global__ __launch_bounds__(256) void prep_kernel(
    const float* __restrict__ adj, uint16_t* __restrict__ adjb, int cvtN,
    const float* __restrict__ Wf, uint16_t* __restrict__ Wp,
    const float* __restrict__ x, const float* __restrict__ h,
    const float* __restrict__ m,
    uint16_t* __restrict__ P, uint16_t* __restrict__ P2)
{
    int bid = blockIdx.x;
    int t = threadIdx.x;

    if (bid < cvtN) {
        size_t i = ((size_t)bid * 256 + t) * 8;
        float4 v0 = *(const float4*)(adj + i);
        float4 v1 = *(const float4*)(adj + i + 4);
        union { uint4 u; uint16_t e[8]; } o;
        o.e[0] = f2bf(v0.x); o.e[1] = f2bf(v0.y); o.e[2] = f2bf(v0.z); o.e[3] = f2bf(v0.w);
        o.e[4] = f2bf(v1.x); o.e[5] = f2bf(v1.y); o.e[6] = f2bf(v1.z); o.e[7] = f2bf(v1.w);
        *(uint4*)(adjb + i) = o.u;
        return;
    }
    bid -= cvtN;

    if (bid < 112) {
        // W: fp32 [14][32][64] -> bf16 Wp[gp][col][slot^swz][k&7]
        int idx = bid * 256 + t;                    // 14*32*64 = 28672
        int g   = idx >> 11;
        int k   = (idx >> 6) & 31;
        int col = idx & 63;
        uint16_t v = f2bf(Wf[idx]);                 // Wf[g][k][col]
        int gp = g >> 1;
        int sl = ((g & 1) << 2) | (k >> 3);
        int ph = sl ^ (col & 7);
        Wp[((gp * 64 + col) * 64) + ph * 8 + (k & 7)] = v;
        return;
    }
    bid -= 112;

    // pack: state [B][N][F] fp32 -> dst[rowbase + b*32 + f][n] bf16
    const float* src; uint16_t* dst; int rowbase, b, n0;
    if (bid < 512) {
        int tensor = bid >> 8;
        src = tensor ? h : x; dst = P; rowbase = tensor * 128;
        b = (bid >> 6) & 3; n0 = (bid & 63) * 64;
    } else {
        int q = bid - 512;
        src = m; dst = P2; rowbase = 128;
        b = q >> 6; n0 = (q & 63) * 64;
    }
    __shared__ uint16_t tl[32][65];
    {
        int i = t >> 2, ch = t & 3;       // node i (0..63), f-chunk ch (8 floats)
        size_t idx = ((size_t)(b * NN + n0 + i)) * FF + ch * 8;
        float4 v0 = *(const float4*)(src + idx);
        float4 v1 = *(const float4*)(src + idx + 4);
        uint16_t e[8] = { f2bf(v0.x), f2bf(v0.y), f2bf(v0.z), f2bf(v0.w),
                          f2bf(v1.x), f2bf(v1.y), f2bf(v1.z), f2bf(v1.w) };
        #pragma unroll
        for (int k = 0; k < 8; k++) tl[ch * 8 + k][i] = e[k];
    }
    __syncthreads();
    {
        int f = t >> 3, ch = t & 7;
        union { uint4 u; uint16_t e[8]; } v;
        #pragma unroll
        for (int k = 0; k < 8; k++) v.e[k] = tl[f][ch * 8 + k];
        size_t row = (size_t)(rowbase + b * 32 + f);
        *(uint4*)(dst + row * NN + n0 + ch * 8) = v.u;
    }
}

// ---------- GEMM: out[c][m] = sum_k adj[m][k] * Bt[c][k]; C fixed = 256 ----------
// 128x128 tile, BK=32, 4 waves (2x2 of 64x64), 16x16x32 bf16 MFMA.
// LDS tile rows are 64B = 4 16B slots; phys_slot = logical_slot ^ ((row>>1)&3)
// (both-sides XOR: swizzled GLOBAL source + linear LDS dest + swizzled ds_read).
// bf16 path stages via global_load_lds width=16 (no VGPR round-trip).
__global__ __launch_bounds__(256) void gemm_kernel(
    const void* __restrict__ Av,      // adj: bf16 (isf32A=0) or fp32 (isf32A=1)
    const uint16_t* __restrict__ Bt,  // [256][4096] bf16
    float* __restrict__ part, uint16_t* __restrict__ Cb,
    int kLen, int direct, int isf32A)
{
    int mt = blockIdx.x, nt = blockIdx.y, ks = blockIdx.z;
    int m0 = mt * 128, c0 = nt * 128, k0 = ks * kLen;
    __shared__ __align__(16) uint16_t aL[128 * 32];
    __shared__ __align__(16) uint16_t bL[128 * 32];
    int t = threadIdx.x;
    int lane = t & 63, w = t >> 6;
    int wm = (w & 1) * 64, wn = (w >> 1) * 64;
    int lm = lane & 15, lk = lane >> 4;

    const uint16_t* A16 = (const uint16_t*)Av;
    const float*    Af  = (const float*)Av;

    f32x4 acc[4][4] = {};

    for (int kk = k0; kk < k0 + kLen; kk += 32) {
        if (!isf32A) {
            #pragma unroll
            for (int q = 0; q < 2; q++) {
                int pos  = q * 4096 + t * 16;            // byte offset into 8KB tile
                int row  = pos >> 6;                     // 64 B per tile row
                int slot = ((pos >> 4) & 3) ^ ((row >> 1) & 3);
                int col  = slot * 8;                     // bf16 element within row
                size_t aidx = (size_t)(m0 + row) * 4096 + kk + col;
                size_t bidx = (size_t)(c0 + row) * 4096 + kk + col;
                __builtin_amdgcn_global_load_lds((as1_cvoid*)(A16 + aidx),
                                                 (as3_void*)((char*)aL + pos), 16, 0, 0);
                __builtin_amdgcn_global_load_lds((as1_cvoid*)(Bt + bidx),
                                                 (as3_void*)((char*)bL + pos), 16, 0, 0);
            }
        } else {
            union { uint4 u; uint16_t e[8]; } sa[2], sb[2];
            #pragma unroll
            for (int q = 0; q < 2; q++) {
                int pos  = q * 4096 + t * 16;
                int row  = pos >> 6;
                int slot = ((pos >> 4) & 3) ^ ((row >> 1) & 3);
                int col  = slot * 8;
                size_t aidx = (size_t)(m0 + row) * 4096 + kk + col;
                size_t bidx = (size_t)(c0 + row) * 4096 + kk + col;
                union { uint4 u[2]; float f[8]; } va;
                va.u[0] = *(const uint4*)(Af + aidx);
                va.u[1] = *(const uint4*)(Af + aidx + 4);
                #pragma unroll
                for (int k = 0; k < 8; k++) sa[q].e[k] = f2bf(va.f[k]);
                sb[q].u = *(const uint4*)(Bt + bidx);
            }
            #pragma unroll
            for (int q = 0; q < 2; q++) {
                int pos = q * 4096 + t * 16;
                *(uint4*)((char*)aL + pos) = sa[q].u;
                *(uint4*)((char*)bL + pos) = sb[q].u;
            }
        }
        __syncthreads();
        s16x8 af[4], bfr[4];
        #pragma unroll
        for (int i = 0; i < 4; i++) {
            int r = wm + i * 16 + lm;
            af[i] = *(const s16x8*)(aL + r * 32 + ((lk ^ ((r >> 1) & 3)) * 8));
        }
        #pragma unroll
        for (int j = 0; j < 4; j++) {
            int r = wn + j * 16 + lm;
            bfr[j] = *(const s16x8*)(bL + r * 32 + ((lk ^ ((r >> 1) & 3)) * 8));
        }
        #pragma unroll
        for (int i = 0; i < 4; i++)
            #pragma unroll
            for (int j = 0; j < 4; j++)
                acc[i][j] = __builtin_amdgcn_mfma_f32_16x16x32_bf16(af[i], bfr[j], acc[i][j], 0, 0, 0);
        __syncthreads();
    }

    // C/D layout: col=lane&15 (c dim), row=(lane>>4)*4+reg (m dim)
    int r4 = (lane >> 4) * 4;
    if (direct) {
        #pragma unroll
        for (int i = 0; i < 4; i++)
            #pragma unroll
            for (int j = 0; j < 4; j++) {
                int c = c0 + wn + j * 16 + lm;
                int mr = m0 + wm + i * 16 + r4;
                union { uint2 u; uint16_t e[4]; } v;
                #pragma unroll
                for (int r = 0; r < 4; r++) v.e[r] = f2bf(acc[i][j][r]);
                *(uint2*)(Cb + (size_t)c * 4096 + mr) = v.u;
            }
    } else {
        #pragma unroll
        for (int i = 0; i < 4; i++)
            #pragma unroll
            for (int j = 0; j < 4; j++) {
                int c = c0 + wn + j * 16 + lm;
                int mr = m0 + wm + i * 16 + r4;
                *(f32x4*)(part + ((size_t)ks * 256 + c) * 4096 + mr) = acc[i][j];
            }
    }
}

// ======================================================================
// fuse1: async split-K reduce (counted vmcnt, per-wave pipeline, no barriers)
//        + MFMA dense (8 gates) + GLU + LSTM update.
// Block = (batch b, 64 nodes); 4 waves; wave w stages & consumes rows w*16..+15.
// ======================================================================
__global__ __launch_bounds__(256) void fuse1_kernel(
    const float* __restrict__ part,   // [ns][256][4096] fp32 (ns>0)
    const uint16_t* __restrict__ Cbi, // [256][4096] bf16 (ns==0)
    const uint16_t* __restrict__ Wp,  // packed W (prep)
    const float* __restrict__ bf_,
    const float* __restrict__ cf,
    float* __restrict__ cnew, uint16_t* __restrict__ S2t, int ns)
{
    __shared__ __align__(16) uint16_t WL[4 * 64 * 64];  // 32 KB (gates 0..7)
    __shared__ __align__(16) float    AL[64 * 68];      // 17.4 KB (pitch 68)
    __shared__ __align__(16) float    BL[512];
    __shared__ __align__(16) uint16_t H1[32 * 72];      // 4.6 KB (pitch 72)
    __shared__ __align__(16) float    SB[2][64 * 64];   // 32 KB staging dbuf

    int t = threadIdx.x;
    int lane = t & 63, w = t >> 6;
    int b = blockIdx.x >> 6, n0 = (blockIdx.x & 63) * 64;

    // bias (plain, small)
    if (t < 128) *(float4*)(BL + t * 4) = *(const float4*)(bf_ + t * 4);

    // W stage via async global_load_lds (linear 32KB; 8 x 1KB per wave) — issued
    // OLDEST so the first counted tile-wait drains it for free.
    #pragma unroll
    for (int q = 0; q < 8; q++) {
        int off = (w * 8 + q) * 512 + lane * 8;
        __builtin_amdgcn_global_load_lds((as1_cvoid*)(Wp + off),
                                         (as3_void*)(WL + off), 16, 0, 0);
    }

    int j = lane & 15, kg = lane >> 4;
    int r4 = kg * 4;

    // prefetch c (in flight under the reduction pipeline)
    float cv[2][4];
    #pragma unroll
    for (int hh = 0; hh < 2; hh++)
        #pragma unroll
        for (int r = 0; r < 4; r++)
            cv[hh][r] = cf[((size_t)(b * NN + n0 + w * 16 + r4 + r)) * FF + j + hh * 16];

    if (ns) {
        issue_tile_f(part, SB[0], w, lane, b, n0);
        if (ns > 1) issue_tile_f(part + (size_t)(256 * 4096), SB[1], w, lane, b, n0);
        float asum[16];
        #pragma unroll
        for (int i = 0; i < 16; i++) asum[i] = 0.0f;
        for (int ks = 0; ks < ns; ks++) {
            if (ks + 1 < ns) WAITV4(); else WAITV0();
            const float* sb = SB[ks & 1];
            #pragma unroll
            for (int i = 0; i < 16; i++)        // stride-1 across lanes: conflict-free
                asum[i] += sb[(w * 16 + i) * 64 + lane];
            if (ks + 2 < ns)
                issue_tile_f(part + (size_t)(ks + 2) * (256 * 4096), SB[ks & 1], w, lane, b, n0);
        }
        #pragma unroll
        for (int i = 0; i < 16; i++) AL[(w * 16 + i) * 68 + lane] = asum[i];
    } else {
        int r = t >> 2, ch = t & 3;
        size_t crow = (r < 32) ? (size_t)(b * 32 + r) : (size_t)(128 + b * 32 + (r - 32));
        const uint16_t* cp = Cbi + crow * 4096 + n0 + ch * 16;
        union { uint4 u; uint16_t e[8]; } v0, v1;
        v0.u = *(const uint4*)(cp);
        v1.u = *(const uint4*)(cp + 8);
        float* al = AL + r * 68 + ch * 16;
        #pragma unroll
        for (int k = 0; k < 4; k++) {
            al[k]      = bf2f(v0.e[k]);  al[4 + k]  = bf2f(v0.e[4 + k]);
            al[8 + k]  = bf2f(v1.e[k]);  al[12 + k] = bf2f(v1.e[4 + k]);
        }
    }
    __syncthreads();

    // A fragments: lane holds A[node = l&15][k = (l>>4)*8 + e]
    s16x8 a_ax, a_ah;
    {
        int col = w * 16 + j;
        #pragma unroll
        for (int e = 0; e < 8; e++) {
            int k = kg * 8 + e;
            a_ax[e] = (short)f2bf(AL[k * 68 + col]);
            a_ah[e] = (short)f2bf(AL[(32 + k) * 68 + col]);
        }
    }

    float s[4][2][4];
    #pragma unroll
    for (int p = 0; p < 4; p++) {
        int g0 = p * 2, g1 = p * 2 + 1;          // even: ax, odd: ah
        f32x4 ac0[4] = {}, ac1[4] = {};
        #pragma unroll
        for (int ct = 0; ct < 4; ct++) {
            int col = ct * 16 + j;
            int ph0 = (kg)     ^ (col & 7);
            int ph1 = (4 + kg) ^ (col & 7);
            s16x8 b0 = *(const s16x8*)(WL + (p * 64 + col) * 64 + ph0 * 8);
            s16x8 b1 = *(const s16x8*)(WL + (p * 64 + col) * 64 + ph1 * 8);
            ac0[ct] = __builtin_amdgcn_mfma_f32_16x16x32_bf16(a_ax, b0, ac0[ct], 0, 0, 0);
            ac1[ct] = __builtin_amdgcn_mfma_f32_16x16x32_bf16(a_ah, b1, ac1[ct], 0, 0, 0);
        }
        // GLU: cols (h*16+j) pair with (32+h*16+j) -> both live in this lane
        #pragma unroll
        for (int hh = 0; hh < 2; hh++)
            #pragma unroll
            for (int r = 0; r < 4; r++) {
                float z0l = ac0[hh][r]     + BL[g0 * 64 + hh * 16 + j];
                float z0r = ac0[2 + hh][r] + BL[g0 * 64 + 32 + hh * 16 + j];
                float z1l = ac1[hh][r]     + BL[g1 * 64 + hh * 16 + j];
                float z1r = ac1[2 + hh][r] + BL[g1 * 64 + 32 + hh * 16 + j];
                s[p][hh][r] = z0l * sig_acc(z0r) + z1l * sig_acc(z1r);
            }
    }

    // LSTM update (pure elementwise in registers)
    #pragma unroll
    for (int hh = 0; hh < 2; hh++) {
        union { uint2 u; uint16_t e[4]; } pk;
        #pragma unroll
        for (int r = 0; r < 4; r++) {
            size_t gidx = ((size_t)(b * NN + n0 + w * 16 + r4 + r)) * FF + j + hh * 16;
            float fg = sig_acc(s[0][hh][r]);
            float ig = sig_acc(s[1][hh][r]);
            float cc = tanhf(s[2][hh][r]);
            float og = sig_acc(s[3][hh][r]);
            float cn = fg * cv[hh][r] + ig * cc;
            cnew[gidx] = cn;
            pk.e[r] = f2bf(og * tanhf(cn));
        }
        *(uint2*)(H1 + (j + hh * 16) * 72 + w * 16 + r4) = pk.u;
    }
    __syncthreads();
    {   // pack h1 -> P2 rows b*32+f (GEMM2 B operand, rows 0..127)
        int fr = t >> 3, ch = t & 7;
        uint4 v = *(const uint4*)(H1 + fr * 72 + ch * 8);
        *(uint4*)(S2t + ((size_t)(b * 32 + fr)) * NN + n0 + ch * 8) = v;
    }
}

// ======================================================================
// fuse2: async split-K reduce + MFMA dense (6 gates) + memory-state update.
// ======================================================================
__global__ __launch_bounds__(256) void fuse2_kernel(
    const float* __restrict__ part,
    const uint16_t* __restrict__ Cbi,
    const uint16_t* __restrict__ Wp,
    const float* __restrict__ bf_,
    const float* __restrict__ mf,
    float* __restrict__ hnew, float* __restrict__ mnew, int ns)
{
    __shared__ __align__(16) uint16_t WL[3 * 64 * 64];  // 24 KB (gates 8..13)
    __shared__ __align__(16) float    AL[64 * 68];
    __shared__ __align__(16) float    BL[384];
    __shared__ __align__(16) float    SB[2][64 * 64];   // 32 KB staging dbuf

    int t = threadIdx.x;
    int lane = t & 63, w = t >> 6;
    int b = blockIdx.x >> 6, n0 = (blockIdx.x & 63) * 64;

    if (t < 96) *(float4*)(BL + t * 4) = *(const float4*)(bf_ + 512 + t * 4);

    // W stage async: 24KB linear (6 x 1KB per wave), gates 8..13
    #pragma unroll
    for (int q = 0; q < 6; q++) {
        int off = (w * 6 + q) * 512 + lane * 8;
        __builtin_amdgcn_global_load_lds((as1_cvoid*)(Wp + 4 * 64 * 64 + off),
                                         (as3_void*)(WL + off), 16, 0, 0);
    }

    int j = lane & 15, kg = lane >> 4;
    int r4 = kg * 4;

    float mv[2][4];
    #pragma unroll
    for (int hh = 0; hh < 2; hh++)
        #pragma unroll
        for (int r = 0; r < 4; r++)
            mv[hh][r] = mf[((size_t)(b * NN + n0 + w * 16 + r4 + r)) * FF + j + hh * 16];

    if (ns) {
        issue_tile_f(part, SB[0], w, lane, b, n0);
        if (ns > 1) issue_tile_f(part + (size_t)(256 * 4096), SB[1], w, lane, b, n0);
        float asum[16];
        #pragma unroll
        for (int i = 0; i < 16; i++) asum[i] = 0.0f;
        for (int ks = 0; ks < ns; ks++) {
            if (ks + 1 < ns) WAITV4(); else WAITV0();
            const float* sb = SB[ks & 1];
            #pragma unroll
            for (int i = 0; i < 16; i++)
                asum[i] += sb[(w * 16 + i) * 64 + lane];
            if (ks + 2 < ns)
                issue_tile_f(part + (size_t)(ks + 2) * (256 * 4096), SB[ks & 1], w, lane, b, n0);
        }
        #pragma unroll
        for (int i = 0; i < 16; i++) AL[(w * 16 + i) * 68 + lane] = asum[i];
    } else {
        int r = t >> 2, ch = t & 3;
        size_t crow = (r < 32) ? (size_t)(b * 32 + r) : (size_t)(128 + b * 32 + (r - 32));
        const uint16_t* cp = Cbi + crow * 4096 + n0 + ch * 16;
        union { uint4 u; uint16_t e[8]; } v0, v1;
        v0.u = *(const uint4*)(cp);
        v1.u = *(const uint4*)(cp + 8);
        float* al = AL + r * 68 + ch * 16;
        #pragma unroll
        for (int k = 0; k < 4; k++) {
            al[k]      = bf2f(v0.e[k]);  al[4 + k]  = bf2f(v0.e[4 + k]);
            al[8 + k]  = bf2f(v1.e[k]);  al[12 + k] = bf2f(v1.e[4 + k]);
        }
    }
    __syncthreads();

    s16x8 a_h1, a_m;
    {
        int col = w * 16 + j;
        #pragma unroll
        for (int e = 0; e < 8; e++) {
            int k = kg * 8 + e;
            a_h1[e] = (short)f2bf(AL[k * 68 + col]);
            a_m[e]  = (short)f2bf(AL[(32 + k) * 68 + col]);
        }
    }

    float s[3][2][4];
    #pragma unroll
    for (int p = 0; p < 3; p++) {
        int g0 = p * 2, g1 = p * 2 + 1;          // local gates; even: ah1, odd: am
        f32x4 ac0[4] = {}, ac1[4] = {};
        #pragma unroll
        for (int ct = 0; ct < 4; ct++) {
            int col = ct * 16 + j;
            int ph0 = (kg)     ^ (col & 7);
            int ph1 = (4 + kg) ^ (col & 7);
            s16x8 b0 = *(const s16x8*)(WL + (p * 64 + col) * 64 + ph0 * 8);
            s16x8 b1 = *(const s16x8*)(WL + (p * 64 + col) * 64 + ph1 * 8);
            ac0[ct] = __builtin_amdgcn_mfma_f32_16x16x32_bf16(a_h1, b0, ac0[ct], 0, 0, 0);
            ac1[ct] = __builtin_amdgcn_mfma_f32_16x16x32_bf16(a_m, b1, ac1[ct], 0, 0, 0);
        }
        #pragma unroll
        for (int hh = 0; hh < 2; hh++)
            #pragma unroll
            for (int r = 0; r < 4; r++) {
                float z0l = ac0[hh][r]     + BL[g0 * 64 + hh * 16 + j];
                float z0r = ac0[2 + hh][r] + BL[g0 * 64 + 32 + hh * 16 + j];
                float z1l = ac1[hh][r]     + BL[g1 * 64 + hh * 16 + j];
                float z1r = ac1[2 + hh][r] + BL[g1 * 64 + 32 + hh * 16 + j];
                s[p][hh][r] = z0l * sig_acc(z0r) + z1l * sig_acc(z1r);
            }
    }

    #pragma unroll
    for (int hh = 0; hh < 2; hh++)
        #pragma unroll
        for (int r = 0; r < 4; r++) {
            size_t gidx = ((size_t)(b * NN + n0 + w * 16 + r4 + r)) * FF + j + hh * 16;
            float i2 = sig_acc(s[0][hh][r]);
            float gg = sig_acc(s[1][hh][r]);
            float o2 = sig_acc(s[2][hh][r]);
            float mn = i2 * mv[hh][r] + (1.0f - i2) * gg;
            mnew[gidx] = mn;
            hnew[gidx] = mn * o2;
        }
}

extern "C" void kernel_launch(void* const* d_in, const int* in_sizes, int n_in,
                              void* d_out, int out_size, void* d_ws, size_t ws_size,
                              hipStream_t stream) {
    (void)in_sizes; (void)n_in; (void)out_size;
    const float* x   = (const float*)d_in[0];
    const float* h   = (const float*)d_in[1];
    const float* c   = (const float*)d_in[2];
    const float* m   = (const float*)d_in[3];
    const float* adj = (const float*)d_in[4];
    const float* W   = (const float*)d_in[5];
    const float* bb  = (const float*)d_in[6];
    float* out = (float*)d_out;

    char* ws = (char*)d_ws;
    // tier A (big ws): bf16 adj copy + global_load_lds GEMM; tier B: fp32-staging GEMM
    int haveAdjb = ws_size >= (size_t)(72u << 20);
    uint16_t* adjb = (uint16_t*)ws;                              // 32 MB (tier A)
    size_t pOff = haveAdjb ? (size_t)(32u << 20) : 0;
    uint16_t* P    = (uint16_t*)(ws + pOff);                     // 2 MB phase-1 B (x,h)
    uint16_t* P2   = (uint16_t*)(ws + pOff + (2u << 20));        // 2 MB phase-2 B (h1,m)
    uint16_t* Cbuf = (uint16_t*)(ws + pOff + (4u << 20));        // 2 MB GEMM out (ns==0 only)
    uint16_t* Wp   = (uint16_t*)(ws + pOff + (6u << 20));        // 112 KB packed W (1MB slot)
    size_t partOff = pOff + (7u << 20);
    float* part = (float*)(ws + partOff);

    if (ws_size < (8u << 20)) return;   // harness ws is ~268MB; safety only
    size_t avail = ws_size - partOff;
    int ns = 0;
    if      (avail >= (size_t)(32u << 20)) ns = 8;
    else if (avail >= (size_t)(16u << 20)) ns = 4;
    else if (avail >= (size_t)( 8u << 20)) ns = 2;
    else if (avail >= (size_t)( 4u << 20)) ns = 1;

    const void* Agemm = haveAdjb ? (const void*)adjb : (const void*)adj;
    int isf32A = haveAdjb ? 0 : 1;
    int cvtN = haveAdjb ? 8192 : 0;

    // ONE prep launch: adj->bf16, W pack, x/h -> P, m -> P2 (all input-only)
    prep_kernel<<<cvtN + 112 + 768, 256, 0, stream>>>(adj, adjb, cvtN, W, Wp, x, h, m, P, P2);

    // phase 1: GEMM1 -> part (ax rows 0..127, ah 128..255)
    if (ns) {
        gemm_kernel<<<dim3(32, 2, ns), 256, 0, stream>>>(Agemm, P, part, nullptr, 4096 / ns, 0, isf32A);
    } else {
        gemm_kernel<<<dim3(32, 2, 1), 256, 0, stream>>>(Agemm, P, nullptr, Cbuf, 4096, 1, isf32A);
    }
    // fuse1: async reduce + dense(MFMA) + GLU + LSTM; c_new + h1 -> P2 rows 0..127
    fuse1_kernel<<<256, 256, 0, stream>>>(part, Cbuf, Wp, bb, c, out + BNF, P2, ns);
    // phase 2: GEMM2 -> part (ah1 rows 0..127, am 128..255)
    if (ns) {
        gemm_kernel<<<dim3(32, 2, ns), 256, 0, stream>>>(Agemm, P2, part, nullptr, 4096 / ns, 0, isf32A);
    } else {
        gemm_kernel<<<dim3(32, 2, 1), 256, 0, stream>>>(Agemm, P2, nullptr, Cbuf, 4096, 1, isf32A);
    }
    fuse2_kernel<<<256, 256, 0, stream>>>(part, Cbuf, Wp, bb, m, out, out + 2 * BNF, ns);
}